// Round 18
// baseline (107.793 us; speedup 1.0000x reference)
//
#include <hip/hip_runtime.h>
#include <stdint.h>

// ---------------- problem constants ----------------
#define B    8192
#define D    256
#define C    7
#define NTOT 8199          // B + C
#define NPAD 8320          // 65 * 128 (padded rows)
#define NT   65            // 128-row tiles
#define NBLK 2145          // 65*66/2 triangular
#define BETAC 0.005f       // 0.5*(1-GAMMA)
#define L2GAMMA (-0.0144995696951151f)  // log2(0.99)
#define KC   (6.25f + 1.25e-7f)         // score offset
#define EC1  9.016844005555771f         // 6.25 * log2(e)
#define EC0  9.016844185925551f         // (6.25+1.25e-7) * log2(e)

using f32x4  = __attribute__((ext_vector_type(4))) float;

__device__ __forceinline__ void async16(const void* src, void* dst) {
    __builtin_amdgcn_global_load_lds(
        (const __attribute__((address_space(1))) void*)src,
        (__attribute__((address_space(3))) void*)dst, 16, 0, 0);
}

#define WAITVM(N) asm volatile("s_waitcnt vmcnt(" #N ")" ::: "memory")
#define BARRIER() do { __builtin_amdgcn_s_barrier(); asm volatile("" ::: "memory"); } while(0)

// ---------------- kernel 0: zero S + hist + lossacc + ticket + ticket2 ----------------
__global__ void kzero(float* __restrict__ z) {
    int t = threadIdx.x;
    for (int i = t; i < 1804; i += 256) z[i] = 0.f;   // bytes 0..7216
}

// ---------------- kernel 1: scan + weights + normalize -> fp8 G + atomic S; last block QR ----------------
__global__ void kaccnorm(const float* __restrict__ feats, const int* __restrict__ labels,
                         float* __restrict__ S, unsigned* __restrict__ G32,
                         int* __restrict__ labs_ext, int* __restrict__ hist,
                         const float* __restrict__ protos, const float* __restrict__ moms,
                         unsigned* __restrict__ ticket2) {
    __shared__ int cnt[256 * 8];        // 8 KB
    __shared__ int tot[8];
    __shared__ float wrow[32];
    __shared__ float sacc[4][7][256];   // 28 KB; reused as QR scratch (16 KB needed)
    __shared__ float vvs[8];
    __shared__ float bcast[8];
    __shared__ int flagL;
    int tid = threadIdx.x, lane = tid & 63, wv = tid >> 6;
    int bid = blockIdx.x;

    // ---- full-batch label scan (every block redundantly; deterministic) ----
    int lab[32];
    #pragma unroll
    for (int q = 0; q < 8; ++q) {
        int4 v = *(const int4*)(labels + tid * 32 + q * 4);
        lab[q * 4 + 0] = v.x; lab[q * 4 + 1] = v.y;
        lab[q * 4 + 2] = v.z; lab[q * 4 + 3] = v.w;
    }
    int myc[8] = {0, 0, 0, 0, 0, 0, 0, 0};
    #pragma unroll
    for (int k = 0; k < 32; ++k) {
        #pragma unroll
        for (int cc = 0; cc < 7; ++cc) myc[cc] += (lab[k] == cc) ? 1 : 0;
    }
    #pragma unroll
    for (int cc = 0; cc < 8; ++cc) cnt[tid * 8 + cc] = myc[cc];
    __syncthreads();
    for (int c = wv; c < C; c += 4) {
        int v[4], partial = 0;
        #pragma unroll
        for (int k = 0; k < 4; ++k) { v[k] = cnt[(lane * 4 + k) * 8 + c]; partial += v[k]; }
        int inc = partial;
        #pragma unroll
        for (int d = 1; d < 64; d <<= 1) {
            int y = __shfl_up(inc, d);
            if (lane >= d) inc += y;
        }
        int run = inc - partial;
        #pragma unroll
        for (int k = 0; k < 4; ++k) { int tmp = v[k]; cnt[(lane * 4 + k) * 8 + c] = run; run += tmp; }
        if (lane == 63) { tot[c] = inc; if (bid == 0) hist[c] = inc; }
    }
    __syncthreads();
    // ---- weights for this block's 32 rows (chunk == bid), one thread serial ----
    if (tid == 0) {
        int loc[7];
        #pragma unroll
        for (int cc = 0; cc < 7; ++cc) loc[cc] = cnt[bid * 8 + cc];
        for (int k = 0; k < 32; ++k) {
            int c2 = labels[bid * 32 + k];
            int r = ++loc[c2];
            wrow[k] = exp2f((float)(tot[c2] - r) * L2GAMMA);
        }
    }
    if (tid < 32) labs_ext[bid * 32 + tid] = labels[bid * 32 + tid];
    if (bid == 0) {
        if (tid < 128) { int i2 = B + tid; labs_ext[i2] = (i2 < NTOT) ? (i2 - B) : -1; }
        for (int i = tid; i < 121 * 64; i += 256) G32[NTOT * 64 + i] = 0u;
    }
    __syncthreads();

    // ---- main: normalize -> fp8, accumulate S (w*f) ----
    float acc7[7][4] = {};
    int base = bid * 32 + wv * 8;
    for (int k = 0; k < 8; ++k) {
        int row = base + k;
        const float4 v = *(const float4*)(feats + (size_t)row * 256 + lane * 4);
        float ss = v.x * v.x + v.y * v.y + v.z * v.z + v.w * v.w;
        #pragma unroll
        for (int off = 1; off < 64; off <<= 1) ss += __shfl_xor(ss, off);
        float rn = 1.f / sqrtf(ss);
        unsigned p = (unsigned)__builtin_amdgcn_cvt_pk_fp8_f32(v.x * rn, v.y * rn, 0, false);
        p = (unsigned)__builtin_amdgcn_cvt_pk_fp8_f32(v.z * rn, v.w * rn, (int)p, true);
        G32[(size_t)row * 64 + lane] = p;
        int c = labels[row];               // wave-uniform
        float wgt = wrow[wv * 8 + k];
        #pragma unroll
        for (int cc = 0; cc < 7; ++cc)
            if (c == cc) {
                acc7[cc][0] += wgt * v.x; acc7[cc][1] += wgt * v.y;
                acc7[cc][2] += wgt * v.z; acc7[cc][3] += wgt * v.w;
            }
    }
    #pragma unroll
    for (int cc = 0; cc < 7; ++cc)
        #pragma unroll
        for (int jj = 0; jj < 4; ++jj) sacc[wv][cc][lane * 4 + jj] = acc7[cc][jj];
    __syncthreads();
    #pragma unroll
    for (int cc = 0; cc < 7; ++cc) {
        float s = sacc[0][cc][tid] + sacc[1][cc][tid] + sacc[2][cc][tid] + sacc[3][cc][tid];
        if (s != 0.f) atomicAdd(&S[cc * 256 + tid], s);
    }
    __syncthreads();   // drain this block's atomics before ticket
    if (tid == 0) { __threadfence(); flagL = (int)atomicAdd(ticket2, 1u); }
    __syncthreads();
    if (flagL != 255) return;

    // ======== last block: inline Householder QR -> proto fp8 rows in G ========
    int t = tid, w = wv, ln = lane;
    float* Aq = &sacc[0][0][0];        // 2048 f32
    float* Vq = Aq + 2048;             // 2048 f32
    __syncthreads();
    #pragma unroll
    for (int c = 0; c < C; ++c) {
        float p = protos[c * 256 + t];
        float m0 = moms[c * 256 + t];
        float gn = exp2f((float)tot[c] * L2GAMMA);
        float sv = atomicAdd(&S[c * 256 + t], 0.f);    // coherent read
        float mf = gn * m0 + BETAC * sv - 0.5f * (1.f - gn) * p;
        Aq[t * 8 + c] = p + mf;
        Vq[t * 8 + c] = 0.f;
    }
    __syncthreads();
    for (int j = 0; j < C; ++j) {
        if (w == 0) {
            float s = 0.f;
            for (int i = ln; i < 256; i += 64) {
                float a = (i >= j) ? Aq[i * 8 + j] : 0.f;
                s += a * a;
            }
            #pragma unroll
            for (int off = 32; off; off >>= 1) s += __shfl_xor(s, off);
            if (ln == 0) {
                float norm = sqrtf(s);
                float alpha = Aq[j * 8 + j];
                float beta = (alpha >= 0.f) ? -norm : norm;
                float vv = 2.f * beta * (beta - alpha);
                bcast[0] = alpha; bcast[1] = beta;
                bcast[2] = (vv > 0.f) ? 1.f : 0.f;
                vvs[j] = (vv > 0.f) ? vv : 1.f;
            }
        }
        __syncthreads();
        float alpha = bcast[0], valid = bcast[2];
        float beta = bcast[1];
        float vi = 0.f;
        if (valid != 0.f) {
            if (t == j) vi = alpha - beta;
            else if (t > j) vi = Aq[t * 8 + j];
        }
        Vq[t * 8 + j] = vi;
        __syncthreads();
        float vvj = vvs[j];
        for (int k = j + 1 + w; k < C; k += 4) {
            float cp = 0.f;
            for (int i = ln; i < 256; i += 64) cp += Vq[i * 8 + j] * Aq[i * 8 + k];
            #pragma unroll
            for (int off = 32; off; off >>= 1) cp += __shfl_xor(cp, off);
            float scale = 2.f * cp / vvj;
            for (int i = ln; i < 256; i += 64) Aq[i * 8 + k] -= scale * Vq[i * 8 + j];
        }
        __syncthreads();
    }
    #pragma unroll
    for (int c = 0; c < C; ++c) Aq[t * 8 + c] = (t == c) ? 1.f : 0.f;
    __syncthreads();
    for (int j = C - 1; j >= 0; --j) {
        float vvj = vvs[j];
        for (int k = w; k < C; k += 4) {
            float cp = 0.f;
            for (int i = ln; i < 256; i += 64) cp += Vq[i * 8 + j] * Aq[i * 8 + k];
            #pragma unroll
            for (int off = 32; off; off >>= 1) cp += __shfl_xor(cp, off);
            float scale = 2.f * cp / vvj;
            for (int i = ln; i < 256; i += 64) Aq[i * 8 + k] -= scale * Vq[i * 8 + j];
        }
        __syncthreads();
    }
    for (int c = w; c < C; c += 4) {
        float s = 0.f;
        for (int i = ln; i < 256; i += 64) { float a = Aq[i * 8 + c]; s += a * a; }
        #pragma unroll
        for (int off = 32; off; off >>= 1) s += __shfl_xor(s, off);
        if (ln == 0) bcast[c] = 1.f / sqrtf(s);
    }
    __syncthreads();
    unsigned char* G8 = (unsigned char*)G32;
    #pragma unroll
    for (int c = 0; c < C; ++c) {
        float val = Aq[t * 8 + c] * bcast[c];
        int pk = __builtin_amdgcn_cvt_pk_fp8_f32(val, 0.f, 0, false);
        G8[(size_t)(B + c) * 256 + t] = (unsigned char)(pk & 0xff);
    }
}

// ---------------- kernel 2: pure kmain — 128x128 symmetric fused G G^T ----------------
__global__ __launch_bounds__(512, 2) void kmain(const unsigned char* __restrict__ G,
                                                const int* __restrict__ labs,
                                                float* __restrict__ pP,
                                                float* __restrict__ pN) {
    __shared__ unsigned char Asm_[128 * 256];   // full-K fp8 A tile (32 KB)
    __shared__ unsigned char Bsm_[128 * 256];   // full-K fp8 B tile (32 KB)
    float* rowP = (float*)Asm_;                 // epilogue overlay [2][128]
    float* rowN = rowP + 256;                   // [2][128]
    float* colP = rowN + 256;                   // [4][128]
    float* colN = colP + 512;                   // [4][128]

    // bijective XCD swizzle: NBLK = 2145 = 8*268 + 1 (residue 0 gets 269)
    int b0 = blockIdx.x;
    int xcd = b0 & 7, pos = b0 >> 3;
    int b = (xcd == 0) ? pos : (269 + (xcd - 1) * 268 + pos);

    // triangular decode
    int jt = (int)((sqrtf(8.f * (float)b + 1.f) - 1.f) * 0.5f);
    while ((jt * (jt + 1)) / 2 > b) --jt;
    while (((jt + 1) * (jt + 2)) / 2 <= b) ++jt;
    int it = b - (jt * (jt + 1)) / 2;

    int rowA = it * 128, rowB = jt * 128;
    int tid = threadIdx.x, lane = tid & 63, w8 = tid >> 6;
    int wr = w8 >> 1, wc = w8 & 1;              // 4x2 wave grid
    int g4 = lane >> 4, q15 = lane & 15;
    const char* gb = (const char*)G;

    // ---- single-shot staging: 8 loads/thread in flight, one wait.
    #pragma unroll
    for (int q = 0; q < 4; ++q) {
        int o = q * 8192 + tid * 16;
        int row = o >> 8, colb = o & 255;
        int sc = colb ^ ((row & 15) << 4);
        async16(gb + (size_t)(rowA + row) * 256 + sc, (char*)Asm_ + o);
    }
    #pragma unroll
    for (int q = 0; q < 4; ++q) {
        int o = q * 8192 + tid * 16;
        int row = o >> 8, colb = o & 255;
        int sc = colb ^ ((row & 15) << 4);
        async16(gb + (size_t)(rowB + row) * 256 + sc, (char*)Bsm_ + o);
    }

    // label prefetch into registers — overlaps the stage latency
    int ljv[4];
    #pragma unroll
    for (int n = 0; n < 4; ++n) ljv[n] = labs[rowB + wc * 64 + n * 16 + q15];
    int4 lrow[2];
    #pragma unroll
    for (int m = 0; m < 2; ++m)
        lrow[m] = *(const int4*)(labs + rowA + wr * 32 + m * 16 + g4 * 4);

    f32x4 acc[2][4];
    #pragma unroll
    for (int m = 0; m < 2; ++m)
        #pragma unroll
        for (int n = 0; n < 4; ++n) acc[m][n] = 0.f;

    WAITVM(0);
    BARRIER();

    // ---- mega K-step: 64 MFMA per wave, no barriers
    #pragma unroll
    for (int kk = 0; kk < 8; ++kk) {
        long af[2], bfr[4];
        int cb = (kk * 32 + g4 * 8) ^ (q15 << 4);
        #pragma unroll
        for (int m = 0; m < 2; ++m) {
            int r0 = wr * 32 + m * 16 + q15;
            af[m] = *(const long*)((const char*)Asm_ + r0 * 256 + cb);
        }
        #pragma unroll
        for (int n = 0; n < 4; ++n) {
            int r0 = wc * 64 + n * 16 + q15;
            bfr[n] = *(const long*)((const char*)Bsm_ + r0 * 256 + cb);
        }
        __builtin_amdgcn_s_setprio(1);
        #pragma unroll
        for (int m = 0; m < 2; ++m)
            #pragma unroll
            for (int n = 0; n < 4; ++n)
                acc[m][n] = __builtin_amdgcn_mfma_f32_16x16x32_fp8_fp8(af[m], bfr[n], acc[m][n], 0, 0, 0);
        __builtin_amdgcn_s_setprio(0);
    }

    __syncthreads();   // all LDS reads done before epilogue overlay writes

    // ---- pos+neg epilogue: s = fma(sim,6.25,KC); e = exp2(fma(sim,EC1,EC0))
    float cs[4] = {0.f, 0.f, 0.f, 0.f}, cn[4] = {0.f, 0.f, 0.f, 0.f};
    bool fastpath = (it != jt) && (jt != NT - 1);

#define EPI(VALIDEXPR)                                                         \
    _Pragma("unroll")                                                          \
    for (int m = 0; m < 2; ++m) {                                              \
        _Pragma("unroll")                                                      \
        for (int r = 0; r < 4; ++r) {                                          \
            int il = wr * 32 + m * 16 + g4 * 4 + r;                            \
            int i = rowA + il; (void)i;                                        \
            int li = ((const int*)&lrow[m])[r];                                \
            float ps = 0.f, ns = 0.f;                                          \
            _Pragma("unroll")                                                  \
            for (int n = 0; n < 4; ++n) {                                      \
                int j = rowB + wc * 64 + n * 16 + q15; (void)j;                \
                float sim = acc[m][n][r];                                      \
                float s = fmaf(sim, 6.25f, KC);                                \
                float e = exp2f(fmaf(sim, EC1, EC0));                          \
                if (VALIDEXPR) {                                               \
                    if (li == ljv[n]) { ps += s; cs[n] += s; }                 \
                    else              { ns += e; cn[n] += e; }                 \
                }                                                              \
            }                                                                  \
            _Pragma("unroll")                                                  \
            for (int off = 1; off < 16; off <<= 1) {                           \
                ps += __shfl_xor(ps, off);                                     \
                ns += __shfl_xor(ns, off);                                     \
            }                                                                  \
            if (q15 == 0) { rowP[wc * 128 + il] = ps; rowN[wc * 128 + il] = ns; } \
        }                                                                      \
    }

    if (fastpath) { EPI(true); }
    else          { EPI(i < NTOT && j < NTOT && i != j); }
#undef EPI

    // col-side: reduce over g4 groups (same q15-column, different rows)
    #pragma unroll
    for (int n = 0; n < 4; ++n) {
        float a = cs[n], bb = cn[n];
        a += __shfl_xor(a, 16); a += __shfl_xor(a, 32);
        bb += __shfl_xor(bb, 16); bb += __shfl_xor(bb, 32);
        if (g4 == 0) {
            colP[wr * 128 + wc * 64 + n * 16 + q15] = a;
            colN[wr * 128 + wc * 64 + n * 16 + q15] = bb;
        }
    }

    __syncthreads();
    if (tid < 128) {
        pP[(size_t)jt * NPAD + rowA + tid] = rowP[tid] + rowP[128 + tid];
        pN[(size_t)jt * NPAD + rowA + tid] = rowN[tid] + rowN[128 + tid];
    } else if (tid < 256 && it != jt) {
        int tt = tid - 128;
        pP[(size_t)it * NPAD + rowB + tt] = colP[tt] + colP[128 + tt] + colP[256 + tt] + colP[384 + tt];
        pN[(size_t)it * NPAD + rowB + tt] = colN[tt] + colN[128 + tt] + colN[256 + tt] + colN[384 + tt];
    }
}

// ---------------- kernel 3: light reduce + masked-mean finalize ----------------
__global__ void kreduce(const float* __restrict__ pP, const float* __restrict__ pN,
                        const int* __restrict__ hist, const int* __restrict__ labs,
                        float* __restrict__ lossacc, unsigned* __restrict__ ticket,
                        float* __restrict__ out) {
    int i = blockIdx.x * 256 + threadIdx.x;
    float lsum = 0.f, lcnt = 0.f;
    if (i < NTOT) {
        float sp = 0.f, sn = 0.f;
        #pragma unroll 5
        for (int c = 0; c < NT; ++c) {
            sp += pP[(size_t)c * NPAD + i];
            sn += pN[(size_t)c * NPAD + i];
        }
        float cnt = (float)hist[labs[i]];
        float pos = sp / (cnt + 1e-8f);
        float neg = logf(sn + 1e-8f);
        float loss = neg - pos;
        if (loss > 0.f) { lsum = loss; lcnt = 1.f; }
    }
    #pragma unroll
    for (int off = 1; off < 64; off <<= 1) {
        lsum += __shfl_xor(lsum, off);
        lcnt += __shfl_xor(lcnt, off);
    }
    __shared__ float s1[4], s2[4];
    int lane = threadIdx.x & 63, w = threadIdx.x >> 6;
    if (lane == 0) { s1[w] = lsum; s2[w] = lcnt; }
    __syncthreads();
    if (threadIdx.x == 0) {
        atomicAdd(&lossacc[0], s1[0] + s1[1] + s1[2] + s1[3]);
        atomicAdd(&lossacc[1], s2[0] + s2[1] + s2[2] + s2[3]);
        __threadfence();
        unsigned tk = atomicAdd(ticket, 1u);
        if (tk == 32) {   // last of 33 blocks
            float a = atomicAdd(&lossacc[0], 0.f);
            float c2 = atomicAdd(&lossacc[1], 0.f);
            out[0] = (c2 > 0.f) ? a / fmaxf(c2, 1.f) : 0.f;
        }
    }
}

// ---------------- launcher ----------------
extern "C" void kernel_launch(void* const* d_in, const int* in_sizes, int n_in,
                              void* d_out, int out_size, void* d_ws, size_t ws_size,
                              hipStream_t stream) {
    const float* feats  = (const float*)d_in[0];
    const int*   labels = (const int*)d_in[1];
    const float* protos = (const float*)d_in[2];
    const float* moms   = (const float*)d_in[3];
    float* out = (float*)d_out;

    char* ws = (char*)d_ws;
    float*    S_      = (float*)(ws + 0);        // 1792 f32  -> 7168
    int*      hist    = (int*)  (ws + 7168);     // 8 int     -> 7200
    float*    lossacc = (float*)(ws + 7200);     // 2 f32     -> 7208
    unsigned* ticket  = (unsigned*)(ws + 7208);  // 1 u32     -> 7212
    unsigned* ticket2 = (unsigned*)(ws + 7212);  // 1 u32     -> 7216
    int*      labs    = (int*)  (ws + 7296);     // 8320 int  -> 40576
    unsigned char* G  = (unsigned char*)(ws + 40704);    // 8320*256 fp8 -> 2170624
    float*    pP      = (float*)(ws + 2170624);  // 65*8320 f32 -> 4333824
    float*    pN      = (float*)(ws + 4333824);  // 65*8320 f32 -> 6497024

    kzero<<<1, 256, 0, stream>>>((float*)ws);
    kaccnorm<<<256, 256, 0, stream>>>(feats, labels, S_, (unsigned*)G, labs, hist,
                                      protos, moms, ticket2);
    kmain<<<NBLK, 512, 0, stream>>>(G, labs, pP, pN);
    kreduce<<<33, 256, 0, stream>>>(pP, pN, hist, labs, lossacc, ticket, out);
}

// Round 19
// 87.229 us; speedup vs baseline: 1.2357x; 1.2357x over previous
//
#include <hip/hip_runtime.h>
#include <stdint.h>

// ---------------- problem constants ----------------
#define B    8192
#define D    256
#define C    7
#define NTOT 8199          // B + C
#define NPAD 8320          // 65 * 128 (padded rows)
#define NT   65            // 128-row tiles
#define NBLK 2145          // 65*66/2 triangular
#define BETAC 0.005f       // 0.5*(1-GAMMA)
#define L2GAMMA (-0.0144995696951151f)  // log2(0.99)
#define KC   (6.25f + 1.25e-7f)         // score offset
#define EC1  9.016844005555771f         // 6.25 * log2(e)
#define EC0  9.016844185925551f         // (6.25+1.25e-7) * log2(e)

using f32x4  = __attribute__((ext_vector_type(4))) float;

__device__ __forceinline__ void async16(const void* src, void* dst) {
    __builtin_amdgcn_global_load_lds(
        (const __attribute__((address_space(1))) void*)src,
        (__attribute__((address_space(3))) void*)dst, 16, 0, 0);
}

#define WAITVM(N) asm volatile("s_waitcnt vmcnt(" #N ")" ::: "memory")
#define BARRIER() do { __builtin_amdgcn_s_barrier(); asm volatile("" ::: "memory"); } while(0)

// ---------------- kernel 0: zero S + lossacc + ticket + flag ----------------
__global__ void kzero(float* __restrict__ z) {
    int t = threadIdx.x;
    for (int i = t; i < 1804; i += 256) z[i] = 0.f;   // bytes 0..7216
}

// ---------------- kernel 1: inline scan + weights + normalize -> fp8 G + atomic S ----------------
__global__ void kaccnorm(const float* __restrict__ feats, const int* __restrict__ labels,
                         float* __restrict__ S, unsigned* __restrict__ G32,
                         int* __restrict__ labs_ext, int* __restrict__ hist) {
    __shared__ int cnt[256 * 8];        // 8 KB
    __shared__ int tot[8];
    __shared__ float wrow[32];
    __shared__ float sacc[4][7][256];   // 28 KB
    int tid = threadIdx.x, lane = tid & 63, wv = tid >> 6;
    int bid = blockIdx.x;

    // ---- full-batch label scan (every block redundantly; deterministic) ----
    int lab[32];
    #pragma unroll
    for (int q = 0; q < 8; ++q) {
        int4 v = *(const int4*)(labels + tid * 32 + q * 4);
        lab[q * 4 + 0] = v.x; lab[q * 4 + 1] = v.y;
        lab[q * 4 + 2] = v.z; lab[q * 4 + 3] = v.w;
    }
    int myc[8] = {0, 0, 0, 0, 0, 0, 0, 0};
    #pragma unroll
    for (int k = 0; k < 32; ++k) {
        #pragma unroll
        for (int cc = 0; cc < 7; ++cc) myc[cc] += (lab[k] == cc) ? 1 : 0;
    }
    #pragma unroll
    for (int cc = 0; cc < 8; ++cc) cnt[tid * 8 + cc] = myc[cc];
    __syncthreads();
    for (int c = wv; c < C; c += 4) {
        int v[4], partial = 0;
        #pragma unroll
        for (int k = 0; k < 4; ++k) { v[k] = cnt[(lane * 4 + k) * 8 + c]; partial += v[k]; }
        int inc = partial;
        #pragma unroll
        for (int d = 1; d < 64; d <<= 1) {
            int y = __shfl_up(inc, d);
            if (lane >= d) inc += y;
        }
        int run = inc - partial;
        #pragma unroll
        for (int k = 0; k < 4; ++k) { int tmp = v[k]; cnt[(lane * 4 + k) * 8 + c] = run; run += tmp; }
        if (lane == 63) { tot[c] = inc; if (bid == 0) hist[c] = inc; }
    }
    __syncthreads();
    // ---- weights for this block's 32 rows (chunk == bid), one thread serial ----
    if (tid == 0) {
        int loc[7];
        #pragma unroll
        for (int cc = 0; cc < 7; ++cc) loc[cc] = cnt[bid * 8 + cc];
        for (int k = 0; k < 32; ++k) {
            int c2 = labels[bid * 32 + k];
            int r = ++loc[c2];
            wrow[k] = exp2f((float)(tot[c2] - r) * L2GAMMA);
        }
    }
    if (tid < 32) labs_ext[bid * 32 + tid] = labels[bid * 32 + tid];
    if (bid == 0) {
        if (tid < 128) { int i2 = B + tid; labs_ext[i2] = (i2 < NTOT) ? (i2 - B) : -1; }
        for (int i = tid; i < 121 * 64; i += 256) G32[NTOT * 64 + i] = 0u;
    }
    __syncthreads();

    // ---- main: normalize -> fp8, accumulate S (w*f) ----
    float acc7[7][4] = {};
    int base = bid * 32 + wv * 8;
    for (int k = 0; k < 8; ++k) {
        int row = base + k;
        const float4 v = *(const float4*)(feats + (size_t)row * 256 + lane * 4);
        float ss = v.x * v.x + v.y * v.y + v.z * v.z + v.w * v.w;
        #pragma unroll
        for (int off = 1; off < 64; off <<= 1) ss += __shfl_xor(ss, off);
        float rn = 1.f / sqrtf(ss);
        unsigned p = (unsigned)__builtin_amdgcn_cvt_pk_fp8_f32(v.x * rn, v.y * rn, 0, false);
        p = (unsigned)__builtin_amdgcn_cvt_pk_fp8_f32(v.z * rn, v.w * rn, (int)p, true);
        G32[(size_t)row * 64 + lane] = p;
        int c = labels[row];               // wave-uniform
        float wgt = wrow[wv * 8 + k];
        #pragma unroll
        for (int cc = 0; cc < 7; ++cc)
            if (c == cc) {
                acc7[cc][0] += wgt * v.x; acc7[cc][1] += wgt * v.y;
                acc7[cc][2] += wgt * v.z; acc7[cc][3] += wgt * v.w;
            }
    }
    #pragma unroll
    for (int cc = 0; cc < 7; ++cc)
        #pragma unroll
        for (int jj = 0; jj < 4; ++jj) sacc[wv][cc][lane * 4 + jj] = acc7[cc][jj];
    __syncthreads();
    #pragma unroll
    for (int cc = 0; cc < 7; ++cc) {
        float s = sacc[0][cc][tid] + sacc[1][cc][tid] + sacc[2][cc][tid] + sacc[3][cc][tid];
        if (s != 0.f) atomicAdd(&S[cc * 256 + tid], s);
    }
}

// ---------------- kernel 2: kmain (pos+neg epilogue) + inline QR (block b==0) ----------------
__global__ __launch_bounds__(512, 2) void kmain(const unsigned char* __restrict__ G,
                                                unsigned* __restrict__ G32w,
                                                const int* __restrict__ labs,
                                                float* __restrict__ pP,
                                                float* __restrict__ pN,
                                                const float* __restrict__ S,
                                                const int* __restrict__ hist,
                                                const float* __restrict__ protos,
                                                const float* __restrict__ moms,
                                                unsigned* __restrict__ flag) {
    __shared__ unsigned char Asm_[128 * 256];   // full-K fp8 A tile (32 KB); QR scratch A
    __shared__ unsigned char Bsm_[128 * 256];   // full-K fp8 B tile (32 KB); QR scratch V
    __shared__ float vvs[8];
    __shared__ float bcast[8];
    float* rowP = (float*)Asm_;                 // [2][128]
    float* rowN = rowP + 256;                   // [2][128]
    float* colP = rowN + 256;                   // [4][128]
    float* colN = colP + 512;                   // [4][128]

    // bijective XCD swizzle: NBLK = 2145 = 8*268 + 1 (residue 0 gets 269)
    int b0 = blockIdx.x;
    int xcd = b0 & 7, pos = b0 >> 3;
    int b = (xcd == 0) ? pos : (269 + (xcd - 1) * 268 + pos);

    // triangular decode
    int jt = (int)((sqrtf(8.f * (float)b + 1.f) - 1.f) * 0.5f);
    while ((jt * (jt + 1)) / 2 > b) --jt;
    while (((jt + 1) * (jt + 2)) / 2 <= b) ++jt;
    int it = b - (jt * (jt + 1)) / 2;

    int rowA = it * 128, rowB = jt * 128;
    int tid = threadIdx.x, lane = tid & 63, w8 = tid >> 6;
    int wr = w8 >> 1, wc = w8 & 1;              // 4x2 wave grid
    int g4 = lane >> 4, q15 = lane & 15;
    const char* gb = (const char*)G;

    // ======== block b==0: inline Householder QR, then set flag ========
    if (b == 0) {
        float* Aq = (float*)Asm_;   // 2048 f32
        float* Vq = (float*)Bsm_;   // 2048 f32
        int t = tid, w = tid >> 6, ln = tid & 63;
        if (tid < 256) {
            #pragma unroll
            for (int c = 0; c < C; ++c) {
                float p = protos[c * 256 + t];
                float m0 = moms[c * 256 + t];
                float gn = exp2f((float)hist[c] * L2GAMMA);
                float mf = gn * m0 + BETAC * S[c * 256 + t] - 0.5f * (1.f - gn) * p;
                Aq[t * 8 + c] = p + mf;
                Vq[t * 8 + c] = 0.f;
            }
        }
        __syncthreads();
        for (int j = 0; j < C; ++j) {
            if (tid < 64) {
                float s = 0.f;
                for (int i = tid; i < 256; i += 64) {
                    float a = (i >= j) ? Aq[i * 8 + j] : 0.f;
                    s += a * a;
                }
                #pragma unroll
                for (int off = 32; off; off >>= 1) s += __shfl_xor(s, off);
                if (tid == 0) {
                    float norm = sqrtf(s);
                    float alpha = Aq[j * 8 + j];
                    float beta = (alpha >= 0.f) ? -norm : norm;
                    float vv = 2.f * beta * (beta - alpha);
                    bcast[0] = alpha; bcast[1] = beta;
                    bcast[2] = (vv > 0.f) ? 1.f : 0.f;
                    vvs[j] = (vv > 0.f) ? vv : 1.f;
                }
            }
            __syncthreads();
            if (tid < 256) {
                float alpha = bcast[0], valid = bcast[2];
                float beta = bcast[1];
                float vi = 0.f;
                if (valid != 0.f) {
                    if (t == j) vi = alpha - beta;
                    else if (t > j) vi = Aq[t * 8 + j];
                }
                Vq[t * 8 + j] = vi;
            }
            __syncthreads();
            if (tid < 256) {
                float vvj = vvs[j];
                for (int k = j + 1 + w; k < C; k += 4) {
                    float cp = 0.f;
                    for (int i = ln; i < 256; i += 64) cp += Vq[i * 8 + j] * Aq[i * 8 + k];
                    #pragma unroll
                    for (int off = 32; off; off >>= 1) cp += __shfl_xor(cp, off);
                    float scale = 2.f * cp / vvj;
                    for (int i = ln; i < 256; i += 64) Aq[i * 8 + k] -= scale * Vq[i * 8 + j];
                }
            }
            __syncthreads();
        }
        if (tid < 256) {
            #pragma unroll
            for (int c = 0; c < C; ++c) Aq[t * 8 + c] = (t == c) ? 1.f : 0.f;
        }
        __syncthreads();
        for (int j = C - 1; j >= 0; --j) {
            if (tid < 256) {
                float vvj = vvs[j];
                for (int k = w; k < C; k += 4) {
                    float cp = 0.f;
                    for (int i = ln; i < 256; i += 64) cp += Vq[i * 8 + j] * Aq[i * 8 + k];
                    #pragma unroll
                    for (int off = 32; off; off >>= 1) cp += __shfl_xor(cp, off);
                    float scale = 2.f * cp / vvj;
                    for (int i = ln; i < 256; i += 64) Aq[i * 8 + k] -= scale * Vq[i * 8 + j];
                }
            }
            __syncthreads();
        }
        if (tid < 256) {
            for (int c = w; c < C; c += 4) {
                float s = 0.f;
                for (int i = ln; i < 256; i += 64) { float a = Aq[i * 8 + c]; s += a * a; }
                #pragma unroll
                for (int off = 32; off; off >>= 1) s += __shfl_xor(s, off);
                if (ln == 0) bcast[c] = 1.f / sqrtf(s);
            }
        }
        __syncthreads();
        if (tid < 256) {
            unsigned char* G8 = (unsigned char*)G32w;
            #pragma unroll
            for (int c = 0; c < C; ++c) {
                float val = Aq[t * 8 + c] * bcast[c];
                int pk = __builtin_amdgcn_cvt_pk_fp8_f32(val, 0.f, 0, false);
                G8[(size_t)(B + c) * 256 + t] = (unsigned char)(pk & 0xff);
            }
        }
        __syncthreads();
        if (tid == 0) { __threadfence(); atomicExch(flag, 1u); }
    }

    // ======== proto-touching blocks wait for the QR flag ========
    bool protoTile = (jt == NT - 1);
    if (protoTile) {
        if (tid == 0) {
            while (atomicAdd(flag, 0u) == 0u) __builtin_amdgcn_s_sleep(32);
        }
        __syncthreads();
    }

    // ---- single-shot staging: 8 loads/thread in flight, one wait.
    #pragma unroll
    for (int q = 0; q < 4; ++q) {
        int o = q * 8192 + tid * 16;
        int row = o >> 8, colb = o & 255;
        int sc = colb ^ ((row & 15) << 4);
        async16(gb + (size_t)(rowA + row) * 256 + sc, (char*)Asm_ + o);
    }
    #pragma unroll
    for (int q = 0; q < 4; ++q) {
        int o = q * 8192 + tid * 16;
        int row = o >> 8, colb = o & 255;
        int sc = colb ^ ((row & 15) << 4);
        async16(gb + (size_t)(rowB + row) * 256 + sc, (char*)Bsm_ + o);
    }

    // label prefetch into registers — overlaps the stage latency
    int ljv[4];
    #pragma unroll
    for (int n = 0; n < 4; ++n) ljv[n] = labs[rowB + wc * 64 + n * 16 + q15];
    int4 lrow[2];
    #pragma unroll
    for (int m = 0; m < 2; ++m)
        lrow[m] = *(const int4*)(labs + rowA + wr * 32 + m * 16 + g4 * 4);

    f32x4 acc[2][4];
    #pragma unroll
    for (int m = 0; m < 2; ++m)
        #pragma unroll
        for (int n = 0; n < 4; ++n) acc[m][n] = 0.f;

    WAITVM(0);
    BARRIER();

    // proto rows may be stale in this XCD's L2 — overwrite from device-scope coherent LOADS
    if (protoTile) {
        if (tid < 448) {
            int c = tid >> 6, l = tid & 63;
            unsigned v = __hip_atomic_load(&G32w[(size_t)(B + c) * 64 + l],
                                           __ATOMIC_RELAXED, __HIP_MEMORY_SCOPE_AGENT);
            int off = c * 256 + ((((l >> 2) ^ c) << 4) | ((l & 3) << 2));
            *(unsigned*)((char*)Bsm_ + off) = v;
            if (it == NT - 1) *(unsigned*)((char*)Asm_ + off) = v;
        }
        __syncthreads();
    }

    // ---- mega K-step: 64 MFMA per wave, no barriers
    #pragma unroll
    for (int kk = 0; kk < 8; ++kk) {
        long af[2], bfr[4];
        int cb = (kk * 32 + g4 * 8) ^ (q15 << 4);
        #pragma unroll
        for (int m = 0; m < 2; ++m) {
            int r0 = wr * 32 + m * 16 + q15;
            af[m] = *(const long*)((const char*)Asm_ + r0 * 256 + cb);
        }
        #pragma unroll
        for (int n = 0; n < 4; ++n) {
            int r0 = wc * 64 + n * 16 + q15;
            bfr[n] = *(const long*)((const char*)Bsm_ + r0 * 256 + cb);
        }
        __builtin_amdgcn_s_setprio(1);
        #pragma unroll
        for (int m = 0; m < 2; ++m)
            #pragma unroll
            for (int n = 0; n < 4; ++n)
                acc[m][n] = __builtin_amdgcn_mfma_f32_16x16x32_fp8_fp8(af[m], bfr[n], acc[m][n], 0, 0, 0);
        __builtin_amdgcn_s_setprio(0);
    }

    __syncthreads();   // all LDS reads done before epilogue overlay writes

    // ---- pos+neg epilogue: s = fma(sim,6.25,KC); e = exp2(fma(sim,EC1,EC0))
    float cs[4] = {0.f, 0.f, 0.f, 0.f}, cn[4] = {0.f, 0.f, 0.f, 0.f};
    bool fastpath = (it != jt) && (jt != NT - 1);

#define EPI(VALIDEXPR)                                                         \
    _Pragma("unroll")                                                          \
    for (int m = 0; m < 2; ++m) {                                              \
        _Pragma("unroll")                                                      \
        for (int r = 0; r < 4; ++r) {                                          \
            int il = wr * 32 + m * 16 + g4 * 4 + r;                            \
            int i = rowA + il; (void)i;                                        \
            int li = ((const int*)&lrow[m])[r];                                \
            float ps = 0.f, ns = 0.f;                                          \
            _Pragma("unroll")                                                  \
            for (int n = 0; n < 4; ++n) {                                      \
                int j = rowB + wc * 64 + n * 16 + q15; (void)j;                \
                float sim = acc[m][n][r];                                      \
                float s = fmaf(sim, 6.25f, KC);                                \
                float e = exp2f(fmaf(sim, EC1, EC0));                          \
                if (VALIDEXPR) {                                               \
                    if (li == ljv[n]) { ps += s; cs[n] += s; }                 \
                    else              { ns += e; cn[n] += e; }                 \
                }                                                              \
            }                                                                  \
            _Pragma("unroll")                                                  \
            for (int off = 1; off < 16; off <<= 1) {                           \
                ps += __shfl_xor(ps, off);                                     \
                ns += __shfl_xor(ns, off);                                     \
            }                                                                  \
            if (q15 == 0) { rowP[wc * 128 + il] = ps; rowN[wc * 128 + il] = ns; } \
        }                                                                      \
    }

    if (fastpath) { EPI(true); }
    else          { EPI(i < NTOT && j < NTOT && i != j); }
#undef EPI

    // col-side: reduce over g4 groups (same q15-column, different rows)
    #pragma unroll
    for (int n = 0; n < 4; ++n) {
        float a = cs[n], bb = cn[n];
        a += __shfl_xor(a, 16); a += __shfl_xor(a, 32);
        bb += __shfl_xor(bb, 16); bb += __shfl_xor(bb, 32);
        if (g4 == 0) {
            colP[wr * 128 + wc * 64 + n * 16 + q15] = a;
            colN[wr * 128 + wc * 64 + n * 16 + q15] = bb;
        }
    }

    __syncthreads();
    if (tid < 128) {
        pP[(size_t)jt * NPAD + rowA + tid] = rowP[tid] + rowP[128 + tid];
        pN[(size_t)jt * NPAD + rowA + tid] = rowN[tid] + rowN[128 + tid];
    } else if (tid < 256 && it != jt) {
        int tt = tid - 128;
        pP[(size_t)it * NPAD + rowB + tt] = colP[tt] + colP[128 + tt] + colP[256 + tt] + colP[384 + tt];
        pN[(size_t)it * NPAD + rowB + tt] = colN[tt] + colN[128 + tt] + colN[256 + tt] + colN[384 + tt];
    }
}

// ---------------- kernel 3: light reduce + masked-mean finalize ----------------
__global__ void kreduce(const float* __restrict__ pP, const float* __restrict__ pN,
                        const int* __restrict__ hist, const int* __restrict__ labs,
                        float* __restrict__ lossacc, unsigned* __restrict__ ticket,
                        float* __restrict__ out) {
    int i = blockIdx.x * 256 + threadIdx.x;
    float lsum = 0.f, lcnt = 0.f;
    if (i < NTOT) {
        float sp = 0.f, sn = 0.f;
        #pragma unroll 5
        for (int c = 0; c < NT; ++c) {
            sp += pP[(size_t)c * NPAD + i];
            sn += pN[(size_t)c * NPAD + i];
        }
        float cnt = (float)hist[labs[i]];
        float pos = sp / (cnt + 1e-8f);
        float neg = logf(sn + 1e-8f);
        float loss = neg - pos;
        if (loss > 0.f) { lsum = loss; lcnt = 1.f; }
    }
    #pragma unroll
    for (int off = 1; off < 64; off <<= 1) {
        lsum += __shfl_xor(lsum, off);
        lcnt += __shfl_xor(lcnt, off);
    }
    __shared__ float s1[4], s2[4];
    int lane = threadIdx.x & 63, w = threadIdx.x >> 6;
    if (lane == 0) { s1[w] = lsum; s2[w] = lcnt; }
    __syncthreads();
    if (threadIdx.x == 0) {
        atomicAdd(&lossacc[0], s1[0] + s1[1] + s1[2] + s1[3]);
        atomicAdd(&lossacc[1], s2[0] + s2[1] + s2[2] + s2[3]);
        __threadfence();
        unsigned tk = atomicAdd(ticket, 1u);
        if (tk == 32) {   // last of 33 blocks
            float a = atomicAdd(&lossacc[0], 0.f);
            float c2 = atomicAdd(&lossacc[1], 0.f);
            out[0] = (c2 > 0.f) ? a / fmaxf(c2, 1.f) : 0.f;
        }
    }
}

// ---------------- launcher ----------------
extern "C" void kernel_launch(void* const* d_in, const int* in_sizes, int n_in,
                              void* d_out, int out_size, void* d_ws, size_t ws_size,
                              hipStream_t stream) {
    const float* feats  = (const float*)d_in[0];
    const int*   labels = (const int*)d_in[1];
    const float* protos = (const float*)d_in[2];
    const float* moms   = (const float*)d_in[3];
    float* out = (float*)d_out;

    char* ws = (char*)d_ws;
    float*    S_      = (float*)(ws + 0);        // 1792 f32  -> 7168
    int*      hist    = (int*)  (ws + 7168);     // 8 int     -> 7200
    float*    lossacc = (float*)(ws + 7200);     // 2 f32     -> 7208
    unsigned* ticket  = (unsigned*)(ws + 7208);  // 1 u32     -> 7212
    unsigned* flag    = (unsigned*)(ws + 7212);  // 1 u32     -> 7216
    int*      labs    = (int*)  (ws + 7296);     // 8320 int  -> 40576
    unsigned char* G  = (unsigned char*)(ws + 40704);    // 8320*256 fp8 -> 2170624
    float*    pP      = (float*)(ws + 2170624);  // 65*8320 f32 -> 4333824
    float*    pN      = (float*)(ws + 4333824);  // 65*8320 f32 -> 6497024

    kzero<<<1, 256, 0, stream>>>((float*)ws);
    kaccnorm<<<256, 256, 0, stream>>>(feats, labels, S_, (unsigned*)G, labs, hist);
    kmain<<<NBLK, 512, 0, stream>>>(G, (unsigned*)G, labs, pP, pN, S_, hist,
                                    protos, moms, flag);
    kreduce<<<33, 256, 0, stream>>>(pP, pN, hist, labs, lossacc, ticket, out);
}